// Round 3
// baseline (3263.936 us; speedup 1.0000x reference)
//
#include <hip/hip_runtime.h>
#include <cstddef>
#include <cstdint>

// K-means (Lloyd, 10 fixed iters): N=1024 pts, K=64 centroids, D=98304.
// d_in[0]=x f32[1024*98304], d_in[1]=centroid f32[64*98304]
// d_out = concat(final state [64*98304] f32, last choice [1024] as f32)
//
// Round 3: (a) dot GEMM via bf16 hi/lo x3 MFMA (unchanged); (b) sorted full
// segment-sum (deterministic, streaming) replaces the incremental change-list
// update (churn stayed high -> 2x row re-reads + serialization); (c) split-D
// reduce fused into assign; (d) centroid norms fused into segsum via per-chunk
// partials (empty clusters keep stale partials == kept old state, consistent).

#define N_PTS  1024
#define K_C    64
#define D_DIM  98304
#define ITERS  10
#define SPLITD 32          // D-split for dot kernel (partial buffer = 8 MB)
#define BM     64          // points per block tile in dot kernel
#define TK     64          // centroids per block tile (all)
#define DC     64          // D-chunk staged in LDS per step
#define LDSP   72          // padded LDS row stride (bf16 elems)
#define NCHK   96          // D / 1024 chunks for segsum / norm partials

typedef __attribute__((ext_vector_type(8))) short bf16x8;
typedef __attribute__((ext_vector_type(4))) float f32x4;

__device__ __forceinline__ unsigned short f2bf(float x) {   // RNE f32->bf16
    unsigned u = __float_as_uint(x);
    u = (u + 0x7FFFu + ((u >> 16) & 1u)) >> 16;
    return (unsigned short)u;
}
__device__ __forceinline__ float bf2f(unsigned short b) {
    return __uint_as_float((unsigned)b << 16);
}
__device__ __forceinline__ void cvt2(float x, unsigned short& h, unsigned short& l) {
    h = f2bf(x);
    l = f2bf(x - bf2f(h));
}

// block-wide sum over 256 threads (valid in all threads after return)
__device__ __forceinline__ float block_sum256(float s) {
    #pragma unroll
    for (int o = 32; o; o >>= 1) s += __shfl_down(s, o);
    __shared__ float red[4];
    int lane = threadIdx.x & 63, w = threadIdx.x >> 6;
    if (lane == 0) red[w] = s;
    __syncthreads();
    return red[0] + red[1] + red[2] + red[3];
}

// ---------------- row squared-norms (X only, once) ----------------
__global__ __launch_bounds__(256) void row_norm2_kernel(const float* __restrict__ A,
                                                        float* __restrict__ out) {
    const float* a = A + (size_t)blockIdx.x * D_DIM;
    float s = 0.f;
    for (int d = threadIdx.x * 4; d < D_DIM; d += 256 * 4) {
        float4 v = *reinterpret_cast<const float4*>(a + d);
        s += v.x * v.x + v.y * v.y + v.z * v.z + v.w * v.w;
    }
    s = block_sum256(s);
    if (threadIdx.x == 0) out[blockIdx.x] = s;
}

// ---------------- dot[n][k] partial via bf16 hi/lo x3 MFMA ----------------
__global__ __launch_bounds__(256) void mfma_dot_kernel(const float* __restrict__ X,
                                                       const float* __restrict__ S,
                                                       float* __restrict__ partial) {
    __shared__ alignas(16) short Ah[BM][LDSP];
    __shared__ alignas(16) short Al[BM][LDSP];
    __shared__ alignas(16) short Bh[TK][LDSP];
    __shared__ alignas(16) short Bl[TK][LDSP];

    const int nblk = blockIdx.x, seg = blockIdx.y;
    const int t = threadIdx.x;
    const int wid = t >> 6, lane = t & 63;
    const int srow = t >> 4;
    const int scol = (t & 15) * 4;

    const int d_begin = seg * (D_DIM / SPLITD);
    const int NCH = (D_DIM / SPLITD) / DC;

    const float* xbase = X + (size_t)(nblk * BM) * D_DIM;
    float4 xr[4], sr[4];

    auto load_chunk = [&](int d0) {
        #pragma unroll
        for (int p = 0; p < 4; ++p) {
            int row = p * 16 + srow;
            xr[p] = *reinterpret_cast<const float4*>(xbase + (size_t)row * D_DIM + d0 + scol);
            sr[p] = *reinterpret_cast<const float4*>(S + (size_t)row * D_DIM + d0 + scol);
        }
    };
    auto store_chunk = [&]() {
        #pragma unroll
        for (int p = 0; p < 4; ++p) {
            int row = p * 16 + srow;
            ushort4 hx, lx, hs, ls;
            cvt2(xr[p].x, hx.x, lx.x); cvt2(xr[p].y, hx.y, lx.y);
            cvt2(xr[p].z, hx.z, lx.z); cvt2(xr[p].w, hx.w, lx.w);
            cvt2(sr[p].x, hs.x, ls.x); cvt2(sr[p].y, hs.y, ls.y);
            cvt2(sr[p].z, hs.z, ls.z); cvt2(sr[p].w, hs.w, ls.w);
            *reinterpret_cast<ushort4*>(&Ah[row][scol]) = hx;
            *reinterpret_cast<ushort4*>(&Al[row][scol]) = lx;
            *reinterpret_cast<ushort4*>(&Bh[row][scol]) = hs;
            *reinterpret_cast<ushort4*>(&Bl[row][scol]) = ls;
        }
    };

    f32x4 acc[4];
    #pragma unroll
    for (int i = 0; i < 4; ++i) acc[i] = f32x4{0.f, 0.f, 0.f, 0.f};

    load_chunk(d_begin);
    for (int c = 0; c < NCH; ++c) {
        __syncthreads();
        store_chunk();
        __syncthreads();
        if (c + 1 < NCH) load_chunk(d_begin + (c + 1) * DC);

        const int ar = wid * 16 + (lane & 15);
        #pragma unroll
        for (int ks = 0; ks < 2; ++ks) {
            const int ko = ks * 32 + (lane >> 4) * 8;
            bf16x8 ah = *reinterpret_cast<const bf16x8*>(&Ah[ar][ko]);
            bf16x8 al = *reinterpret_cast<const bf16x8*>(&Al[ar][ko]);
            #pragma unroll
            for (int nb = 0; nb < 4; ++nb) {
                const int br = nb * 16 + (lane & 15);
                bf16x8 bh = *reinterpret_cast<const bf16x8*>(&Bh[br][ko]);
                bf16x8 bl = *reinterpret_cast<const bf16x8*>(&Bl[br][ko]);
                acc[nb] = __builtin_amdgcn_mfma_f32_16x16x32_bf16(ah, bh, acc[nb], 0, 0, 0);
                acc[nb] = __builtin_amdgcn_mfma_f32_16x16x32_bf16(ah, bl, acc[nb], 0, 0, 0);
                acc[nb] = __builtin_amdgcn_mfma_f32_16x16x32_bf16(al, bh, acc[nb], 0, 0, 0);
            }
        }
    }

    #pragma unroll
    for (int nb = 0; nb < 4; ++nb)
        #pragma unroll
        for (int r = 0; r < 4; ++r) {
            int row = wid * 16 + (lane >> 4) * 4 + r;
            int col = nb * 16 + (lane & 15);
            int n = nblk * BM + row;
            partial[((size_t)seg * N_PTS + n) * K_C + col] = acc[nb][r];
        }
}

// ---------------- reduce split-D partials (init path only) ----------------
__global__ __launch_bounds__(256) void reduce_dot_kernel(const float* __restrict__ partial,
                                                         float* __restrict__ dot) {
    int i = blockIdx.x * 256 + threadIdx.x;
    float s = 0.f;
    #pragma unroll
    for (int p = 0; p < SPLITD; ++p) s += partial[(size_t)p * N_PTS * K_C + i];
    dot[i] = s;
}

// ---------------- init: per-centroid argmin over points ----------------
__global__ __launch_bounds__(256) void argmin_n_kernel(const float* __restrict__ dot,
                                                       const float* __restrict__ x2,
                                                       int* __restrict__ choice_pts) {
    int k = blockIdx.x;
    float best = 3.4e38f; int bi = N_PTS;
    for (int n = threadIdx.x; n < N_PTS; n += 256) {
        float v = fmaf(-2.f, dot[n * K_C + k], x2[n]);
        if (v < best || (v == best && n < bi)) { best = v; bi = n; }
    }
    #pragma unroll
    for (int off = 32; off; off >>= 1) {
        float v2 = __shfl_down(best, off);
        int   i2 = __shfl_down(bi, off);
        if (v2 < best || (v2 == best && i2 < bi)) { best = v2; bi = i2; }
    }
    __shared__ float bv[4]; __shared__ int bix[4];
    int lane = threadIdx.x & 63, wid = threadIdx.x >> 6;
    if (lane == 0) { bv[wid] = best; bix[wid] = bi; }
    __syncthreads();
    if (threadIdx.x == 0) {
        for (int w = 1; w < 4; ++w)
            if (bv[w] < best || (bv[w] == best && bix[w] < bi)) { best = bv[w]; bi = bix[w]; }
        choice_pts[k] = bi;
    }
}

// ---------------- gather snapped centroids ----------------
__global__ __launch_bounds__(256) void gather_kernel(const float* __restrict__ X,
                                                     const int* __restrict__ choice_pts,
                                                     float* __restrict__ state) {
    int k = blockIdx.x;
    int c = choice_pts[k];
    size_t d = (size_t)blockIdx.y * 1024 + threadIdx.x * 4;
    float4 v = *reinterpret_cast<const float4*>(X + (size_t)c * D_DIM + d);
    *reinterpret_cast<float4*>(state + (size_t)k * D_DIM + d) = v;
}

// ---------------- per-(k,chunk) centroid norm partials (init path) ----------------
__global__ __launch_bounds__(256) void init_normp_kernel(const float* __restrict__ state,
                                                         float* __restrict__ normp) {
    int k = blockIdx.x;
    size_t d = (size_t)blockIdx.y * 1024 + threadIdx.x * 4;
    float4 v = *reinterpret_cast<const float4*>(state + (size_t)k * D_DIM + d);
    float s = block_sum256(v.x * v.x + v.y * v.y + v.z * v.z + v.w * v.w);
    if (threadIdx.x == 0) normp[k * NCHK + blockIdx.y] = s;
}

// ---------------- assign: fused split-D reduce + argmin over K=64 ----------------
// score(n,k) = c2[k] - 2*dot[n][k] (x2 drops out). Tie-break: lowest k.
__global__ __launch_bounds__(256) void assign_kernel(const float* __restrict__ partial,
                                                     const float* __restrict__ normp,
                                                     int* __restrict__ choice) {
    int wid = threadIdx.x >> 6, lane = threadIdx.x & 63;
    int n = blockIdx.x * 4 + wid;
    float s = 0.f;
    #pragma unroll
    for (int p = 0; p < SPLITD; ++p) s += partial[((size_t)p * N_PTS + n) * K_C + lane];
    float c2 = 0.f;
    const float* np = normp + lane * NCHK;
    #pragma unroll 8
    for (int c = 0; c < NCHK; ++c) c2 += np[c];
    float v = fmaf(-2.f, s, c2);
    int bi = lane;
    #pragma unroll
    for (int m = 32; m; m >>= 1) {
        float v2 = __shfl_xor(v, m);
        int   i2 = __shfl_xor(bi, m);
        if (v2 < v || (v2 == v && i2 < bi)) { v = v2; bi = i2; }
    }
    if (lane == 0) choice[n] = bi;
}

// ---------------- deterministic counting sort (1 block, 1024 threads) ----------------
__global__ __launch_bounds__(1024) void sort_kernel(const int* __restrict__ choice,
                                                    int* __restrict__ order,
                                                    int* __restrict__ cstart) {
    __shared__ int ch[N_PTS];
    __shared__ int cnt[K_C];
    __shared__ int cst[K_C + 1];
    int t = threadIdx.x;
    if (t < K_C) cnt[t] = 0;
    __syncthreads();
    int c = choice[t];
    ch[t] = c;
    atomicAdd(&cnt[c], 1);             // integer atomic: deterministic
    __syncthreads();
    if (t == 0) {
        int a = 0;
        for (int k = 0; k < K_C; ++k) { cst[k] = a; a += cnt[k]; }
        cst[K_C] = a;
    }
    __syncthreads();
    if (t <= K_C) cstart[t] = cst[t];
    int r = 0;                          // stable rank: #{m<t : ch[m]==c}
    for (int m = 0; m < t; ++m) r += (ch[m] == c);
    order[cst[c] + r] = t;
}

// ---------------- full segment-sum + mean + fused norm partial ----------------
// grid (K_C, NCHK). Ascending-n order within cluster (deterministic).
// Empty clusters: keep old state AND old normp (consistent pair).
__global__ __launch_bounds__(256) void segsum_kernel(const float* __restrict__ X,
                                                     const int* __restrict__ order,
                                                     const int* __restrict__ cstart,
                                                     float* __restrict__ state,
                                                     float* __restrict__ normp) {
    int k = blockIdx.x;
    int b = cstart[k], e = cstart[k + 1];
    if (b == e) return;
    size_t d = (size_t)blockIdx.y * 1024 + threadIdx.x * 4;
    float ax = 0.f, ay = 0.f, az = 0.f, aw = 0.f;
    for (int i = b; i < e; ++i) {
        const float4 v = *reinterpret_cast<const float4*>(X + (size_t)order[i] * D_DIM + d);
        ax += v.x; ay += v.y; az += v.z; aw += v.w;
    }
    float inv = 1.f / (float)(e - b);
    float4 o; o.x = ax * inv; o.y = ay * inv; o.z = az * inv; o.w = aw * inv;
    *reinterpret_cast<float4*>(state + (size_t)k * D_DIM + d) = o;
    float s = block_sum256(o.x * o.x + o.y * o.y + o.z * o.z + o.w * o.w);
    if (threadIdx.x == 0) normp[k * NCHK + blockIdx.y] = s;
}

// ---------------- write last-iteration assignments as float ----------------
__global__ __launch_bounds__(256) void choice_out_kernel(const int* __restrict__ choice,
                                                         float* __restrict__ out) {
    int n = blockIdx.x * 256 + threadIdx.x;
    if (n < N_PTS) out[n] = (float)choice[n];
}

extern "C" void kernel_launch(void* const* d_in, const int* in_sizes, int n_in,
                              void* d_out, int out_size, void* d_ws, size_t ws_size,
                              hipStream_t stream) {
    const float* X  = (const float*)d_in[0];
    const float* C0 = (const float*)d_in[1];
    float* state      = (float*)d_out;
    float* out_choice = state + (size_t)K_C * D_DIM;

    // workspace (~8.7 MB)
    char* w = (char*)d_ws;
    size_t off = 0;
    float* partial = (float*)(w + off); off += (size_t)SPLITD * N_PTS * K_C * 4;  // 8 MB
    float* dotb    = (float*)(w + off); off += (size_t)N_PTS * K_C * 4;           // 256 KB
    float* x2      = (float*)(w + off); off += (size_t)N_PTS * 4;
    float* normp   = (float*)(w + off); off += (size_t)K_C * NCHK * 4;            // 24 KB
    int* cpts      = (int*)(w + off);   off += 256;
    int* choice    = (int*)(w + off);   off += (size_t)N_PTS * 4;
    int* order     = (int*)(w + off);   off += (size_t)N_PTS * 4;
    int* cstart    = (int*)(w + off);   off += 512;

    dim3 b256(256);

    row_norm2_kernel<<<N_PTS, b256, 0, stream>>>(X, x2);

    // ---- init ('resuming'): snap each centroid to its nearest sample ----
    mfma_dot_kernel<<<dim3(N_PTS / BM, SPLITD), b256, 0, stream>>>(X, C0, partial);
    reduce_dot_kernel<<<dim3(N_PTS * K_C / 256), b256, 0, stream>>>(partial, dotb);
    argmin_n_kernel<<<K_C, b256, 0, stream>>>(dotb, x2, cpts);
    gather_kernel<<<dim3(K_C, NCHK), b256, 0, stream>>>(X, cpts, state);
    init_normp_kernel<<<dim3(K_C, NCHK), b256, 0, stream>>>(state, normp);

    // ---- 10 Lloyd iterations ----
    for (int it = 0; it < ITERS; ++it) {
        mfma_dot_kernel<<<dim3(N_PTS / BM, SPLITD), b256, 0, stream>>>(X, state, partial);
        assign_kernel<<<dim3(N_PTS / 4), b256, 0, stream>>>(partial, normp, choice);
        sort_kernel<<<1, dim3(1024), 0, stream>>>(choice, order, cstart);
        segsum_kernel<<<dim3(K_C, NCHK), b256, 0, stream>>>(X, order, cstart, state, normp);
    }

    choice_out_kernel<<<dim3(N_PTS / 256), b256, 0, stream>>>(choice, out_choice);
}

// Round 4
// 2003.797 us; speedup vs baseline: 1.6289x; 1.6289x over previous
//
#include <hip/hip_runtime.h>
#include <cstddef>
#include <cstdint>

// K-means (Lloyd, 10 fixed iters): N=1024 pts, K=64 centroids, D=98304.
// d_in[0]=x f32[1024*98304], d_in[1]=centroid f32[64*98304]
// d_out = concat(final state [64*98304] f32, last choice [1024] as f32)
//
// Round 4: (a) X pre-converted ONCE to bf16 hi/lo planes in ws (ws ~1.5 GiB per
// harness fill evidence) -> dot kernel is a pure bf16 x3-MFMA GEMM, SPLITD=64
// for 1024 blocks (4/CU), same-seg blocks share an XCD L2 for centroid tiles;
// (b) incremental update via per-cluster SORTED add/sub change lists
// (cost ~ churn, no full-list scan, no full X re-read).

#define N_PTS  1024
#define K_C    64
#define D_DIM  98304
#define ITERS  10
#define SPLITD 64          // D-split for dot kernel (partial = 16 MB)
#define BM     64          // X rows per block tile
#define DC     64          // K-chunk (bf16 elems) staged in LDS per step
#define LDSP   72          // padded LDS row stride (bf16): 144B -> 2-way max (free)
#define NCHK   96          // D/1024 chunks for update kernel
#define CCHK   12          // D/8192 chunks for convert kernels

typedef __attribute__((ext_vector_type(8))) short bf16x8;
typedef __attribute__((ext_vector_type(4))) float f32x4;

__device__ __forceinline__ unsigned short f2bf(float x) {   // RNE f32->bf16
    unsigned u = __float_as_uint(x);
    u = (u + 0x7FFFu + ((u >> 16) & 1u)) >> 16;
    return (unsigned short)u;
}
__device__ __forceinline__ float bf2f(unsigned short b) {
    return __uint_as_float((unsigned)b << 16);
}
__device__ __forceinline__ void cvt2(float x, unsigned short& h, unsigned short& l) {
    h = f2bf(x);
    l = f2bf(x - bf2f(h));
}

__device__ __forceinline__ float block_sum256(float s) {
    #pragma unroll
    for (int o = 32; o; o >>= 1) s += __shfl_down(s, o);
    __shared__ float red[4];
    int lane = threadIdx.x & 63, w = threadIdx.x >> 6;
    if (lane == 0) red[w] = s;
    __syncthreads();
    return red[0] + red[1] + red[2] + red[3];
}

// ---------------- convert rows fp32 -> bf16 hi/lo planes + sumsq partials ----------------
// grid (rows, CCHK); each block converts 8192 elems of one row.
__global__ __launch_bounds__(256) void convert_kernel(const float* __restrict__ A,
                                                      unsigned short* __restrict__ Ph,
                                                      unsigned short* __restrict__ Pl,
                                                      float* __restrict__ sq_part) {
    const int n = blockIdx.x, j = blockIdx.y;
    const size_t base = (size_t)n * D_DIM + (size_t)j * 8192;
    const int t = threadIdx.x;
    float ss = 0.f;
    #pragma unroll
    for (int i = 0; i < 4; ++i) {
        size_t e = base + (size_t)i * 2048 + t * 8;
        float4 a = *reinterpret_cast<const float4*>(A + e);
        float4 b = *reinterpret_cast<const float4*>(A + e + 4);
        ss += a.x*a.x + a.y*a.y + a.z*a.z + a.w*a.w;
        ss += b.x*b.x + b.y*b.y + b.z*b.z + b.w*b.w;
        ushort4 h0, l0, h1, l1;
        cvt2(a.x, h0.x, l0.x); cvt2(a.y, h0.y, l0.y);
        cvt2(a.z, h0.z, l0.z); cvt2(a.w, h0.w, l0.w);
        cvt2(b.x, h1.x, l1.x); cvt2(b.y, h1.y, l1.y);
        cvt2(b.z, h1.z, l1.z); cvt2(b.w, h1.w, l1.w);
        *reinterpret_cast<ushort4*>(Ph + e)     = h0;
        *reinterpret_cast<ushort4*>(Ph + e + 4) = h1;
        *reinterpret_cast<ushort4*>(Pl + e)     = l0;
        *reinterpret_cast<ushort4*>(Pl + e + 4) = l1;
    }
    ss = block_sum256(ss);
    if (t == 0) sq_part[n * CCHK + j] = ss;
}

// ---------------- reduce per-chunk sumsq partials to per-row norms ----------------
__global__ __launch_bounds__(256) void reduce_sq_kernel(const float* __restrict__ sq_part,
                                                        float* __restrict__ out, int rows) {
    int n = blockIdx.x * 256 + threadIdx.x;
    if (n >= rows) return;
    float s = 0.f;
    #pragma unroll
    for (int j = 0; j < CCHK; ++j) s += sq_part[n * CCHK + j];
    out[n] = s;
}

// ---------------- dot[n][k] partial: pure bf16 hi/lo x3 MFMA ----------------
// grid (SPLITD, N/BM): blockIdx.x = seg (same-seg -> same XCD: 64%8==0),
// blockIdx.y = nblk. 256 thr = 4 waves, wave owns 16-row strip x 64 cols.
__global__ __launch_bounds__(256) void mfma_dot_kernel(const unsigned short* __restrict__ Xh,
                                                       const unsigned short* __restrict__ Xl,
                                                       const unsigned short* __restrict__ Sh,
                                                       const unsigned short* __restrict__ Sl,
                                                       float* __restrict__ partial) {
    __shared__ alignas(16) short Ah[BM][LDSP];
    __shared__ alignas(16) short Al[BM][LDSP];
    __shared__ alignas(16) short Bh[K_C][LDSP];
    __shared__ alignas(16) short Bl[K_C][LDSP];

    const int seg = blockIdx.x, nblk = blockIdx.y;
    const int t = threadIdx.x;
    const int wid = t >> 6, lane = t & 63;

    const int d_begin = seg * (D_DIM / SPLITD);
    const int NCH = (D_DIM / SPLITD) / DC;          // 24

    const size_t xrow0 = (size_t)(nblk * BM) * D_DIM;
    // staging slots: group g = t + 256*i (i=0,1): row = g>>3, colg = g&7 (8 bf16)
    const int r0 = t >> 3, c0 = (t & 7) * 8;
    const int r1 = (t + 256) >> 3, c1 = c0;

    ushort4 xh0a, xh0b, xh1a, xh1b, xl0a, xl0b, xl1a, xl1b;
    ushort4 sh0a, sh0b, sh1a, sh1b, sl0a, sl0b, sl1a, sl1b;

    auto load_chunk = [&](int d0) {
        const size_t ax0 = xrow0 + (size_t)r0 * D_DIM + d0 + c0;
        const size_t ax1 = xrow0 + (size_t)r1 * D_DIM + d0 + c1;
        const size_t bs0 = (size_t)r0 * D_DIM + d0 + c0;
        const size_t bs1 = (size_t)r1 * D_DIM + d0 + c1;
        xh0a = *reinterpret_cast<const ushort4*>(Xh + ax0);
        xh0b = *reinterpret_cast<const ushort4*>(Xh + ax0 + 4);
        xh1a = *reinterpret_cast<const ushort4*>(Xh + ax1);
        xh1b = *reinterpret_cast<const ushort4*>(Xh + ax1 + 4);
        xl0a = *reinterpret_cast<const ushort4*>(Xl + ax0);
        xl0b = *reinterpret_cast<const ushort4*>(Xl + ax0 + 4);
        xl1a = *reinterpret_cast<const ushort4*>(Xl + ax1);
        xl1b = *reinterpret_cast<const ushort4*>(Xl + ax1 + 4);
        sh0a = *reinterpret_cast<const ushort4*>(Sh + bs0);
        sh0b = *reinterpret_cast<const ushort4*>(Sh + bs0 + 4);
        sh1a = *reinterpret_cast<const ushort4*>(Sh + bs1);
        sh1b = *reinterpret_cast<const ushort4*>(Sh + bs1 + 4);
        sl0a = *reinterpret_cast<const ushort4*>(Sl + bs0);
        sl0b = *reinterpret_cast<const ushort4*>(Sl + bs0 + 4);
        sl1a = *reinterpret_cast<const ushort4*>(Sl + bs1);
        sl1b = *reinterpret_cast<const ushort4*>(Sl + bs1 + 4);
    };
    auto store_chunk = [&]() {
        *reinterpret_cast<ushort4*>(&Ah[r0][c0])     = xh0a;
        *reinterpret_cast<ushort4*>(&Ah[r0][c0 + 4]) = xh0b;
        *reinterpret_cast<ushort4*>(&Ah[r1][c1])     = xh1a;
        *reinterpret_cast<ushort4*>(&Ah[r1][c1 + 4]) = xh1b;
        *reinterpret_cast<ushort4*>(&Al[r0][c0])     = xl0a;
        *reinterpret_cast<ushort4*>(&Al[r0][c0 + 4]) = xl0b;
        *reinterpret_cast<ushort4*>(&Al[r1][c1])     = xl1a;
        *reinterpret_cast<ushort4*>(&Al[r1][c1 + 4]) = xl1b;
        *reinterpret_cast<ushort4*>(&Bh[r0][c0])     = sh0a;
        *reinterpret_cast<ushort4*>(&Bh[r0][c0 + 4]) = sh0b;
        *reinterpret_cast<ushort4*>(&Bh[r1][c1])     = sh1a;
        *reinterpret_cast<ushort4*>(&Bh[r1][c1 + 4]) = sh1b;
        *reinterpret_cast<ushort4*>(&Bl[r0][c0])     = sl0a;
        *reinterpret_cast<ushort4*>(&Bl[r0][c0 + 4]) = sl0b;
        *reinterpret_cast<ushort4*>(&Bl[r1][c1])     = sl1a;
        *reinterpret_cast<ushort4*>(&Bl[r1][c1 + 4]) = sl1b;
    };

    f32x4 acc[4];
    #pragma unroll
    for (int i = 0; i < 4; ++i) acc[i] = f32x4{0.f, 0.f, 0.f, 0.f};

    load_chunk(d_begin);
    for (int c = 0; c < NCH; ++c) {
        __syncthreads();              // prior chunk's frag reads done
        store_chunk();
        __syncthreads();              // tiles visible
        if (c + 1 < NCH) load_chunk(d_begin + (c + 1) * DC);   // prefetch over MFMAs

        const int ar = wid * 16 + (lane & 15);
        #pragma unroll
        for (int ks = 0; ks < 2; ++ks) {
            const int ko = ks * 32 + (lane >> 4) * 8;
            bf16x8 ah = *reinterpret_cast<const bf16x8*>(&Ah[ar][ko]);
            bf16x8 al = *reinterpret_cast<const bf16x8*>(&Al[ar][ko]);
            #pragma unroll
            for (int nb = 0; nb < 4; ++nb) {
                const int br = nb * 16 + (lane & 15);
                bf16x8 bh = *reinterpret_cast<const bf16x8*>(&Bh[br][ko]);
                bf16x8 bl = *reinterpret_cast<const bf16x8*>(&Bl[br][ko]);
                acc[nb] = __builtin_amdgcn_mfma_f32_16x16x32_bf16(ah, bh, acc[nb], 0, 0, 0);
                acc[nb] = __builtin_amdgcn_mfma_f32_16x16x32_bf16(ah, bl, acc[nb], 0, 0, 0);
                acc[nb] = __builtin_amdgcn_mfma_f32_16x16x32_bf16(al, bh, acc[nb], 0, 0, 0);
            }
        }
    }

    #pragma unroll
    for (int nb = 0; nb < 4; ++nb)
        #pragma unroll
        for (int r = 0; r < 4; ++r) {
            int row = wid * 16 + (lane >> 4) * 4 + r;
            int col = nb * 16 + (lane & 15);
            int n = nblk * BM + row;
            partial[((size_t)seg * N_PTS + n) * K_C + col] = acc[nb][r];
        }
}

// ---------------- reduce split-D partials (init path only) ----------------
__global__ __launch_bounds__(256) void reduce_dot_kernel(const float* __restrict__ partial,
                                                         float* __restrict__ dot) {
    int i = blockIdx.x * 256 + threadIdx.x;
    float s = 0.f;
    #pragma unroll 8
    for (int p = 0; p < SPLITD; ++p) s += partial[(size_t)p * N_PTS * K_C + i];
    dot[i] = s;
}

// ---------------- init: per-centroid argmin over points ----------------
__global__ __launch_bounds__(256) void argmin_n_kernel(const float* __restrict__ dot,
                                                       const float* __restrict__ x2,
                                                       int* __restrict__ choice_pts) {
    int k = blockIdx.x;
    float best = 3.4e38f; int bi = N_PTS;
    for (int n = threadIdx.x; n < N_PTS; n += 256) {
        float v = fmaf(-2.f, dot[n * K_C + k], x2[n]);
        if (v < best || (v == best && n < bi)) { best = v; bi = n; }
    }
    #pragma unroll
    for (int off = 32; off; off >>= 1) {
        float v2 = __shfl_down(best, off);
        int   i2 = __shfl_down(bi, off);
        if (v2 < best || (v2 == best && i2 < bi)) { best = v2; bi = i2; }
    }
    __shared__ float bv[4]; __shared__ int bix[4];
    int lane = threadIdx.x & 63, wid = threadIdx.x >> 6;
    if (lane == 0) { bv[wid] = best; bix[wid] = bi; }
    __syncthreads();
    if (threadIdx.x == 0) {
        for (int w = 1; w < 4; ++w)
            if (bv[w] < best || (bv[w] == best && bix[w] < bi)) { best = bv[w]; bi = bix[w]; }
        choice_pts[k] = bi;
    }
}

// ---------------- gather snapped centroids ----------------
__global__ __launch_bounds__(256) void gather_kernel(const float* __restrict__ X,
                                                     const int* __restrict__ choice_pts,
                                                     float* __restrict__ state) {
    int k = blockIdx.x;
    int c = choice_pts[k];
    size_t d = (size_t)blockIdx.y * 1024 + threadIdx.x * 4;
    float4 v = *reinterpret_cast<const float4*>(X + (size_t)c * D_DIM + d);
    *reinterpret_cast<float4*>(state + (size_t)k * D_DIM + d) = v;
}

// ---------------- assign: fused split-D reduce + argmin over K=64 ----------------
__global__ __launch_bounds__(256) void assign_kernel(const float* __restrict__ partial,
                                                     const float* __restrict__ c2p,
                                                     int* __restrict__ choice) {
    int wid = threadIdx.x >> 6, lane = threadIdx.x & 63;
    int n = blockIdx.x * 4 + wid;
    float s = 0.f;
    #pragma unroll 8
    for (int p = 0; p < SPLITD; ++p) s += partial[((size_t)p * N_PTS + n) * K_C + lane];
    float c2 = 0.f;
    #pragma unroll
    for (int j = 0; j < CCHK; ++j) c2 += c2p[lane * CCHK + j];
    float v = fmaf(-2.f, s, c2);
    int bi = lane;
    #pragma unroll
    for (int m = 32; m; m >>= 1) {
        float v2 = __shfl_xor(v, m);
        int   i2 = __shfl_xor(bi, m);
        if (v2 < v || (v2 == v && i2 < bi)) { v = v2; bi = i2; }
    }
    if (lane == 0) choice[n] = bi;
}

// ---------------- init prev-assignment state ----------------
__global__ __launch_bounds__(256) void init_prev_kernel(int* __restrict__ chp,
                                                        int* __restrict__ ctp) {
    int t = blockIdx.x * 256 + threadIdx.x;
    if (t < N_PTS) chp[t] = -1;
    if (t < K_C)   ctp[t] = 0;
}

// ---------------- sorted change lists (1 block, 1024 thr, deterministic) ----------------
// add_n: changed points sorted by NEW cluster (ascending n within cluster);
// sub_n: changed points (with old>=0) sorted by OLD cluster.
__global__ __launch_bounds__(1024) void changes_kernel(const int* __restrict__ ch_new,
                                                       const int* __restrict__ ch_prev,
                                                       int* __restrict__ add_n,
                                                       int* __restrict__ astart,
                                                       int* __restrict__ sub_n,
                                                       int* __restrict__ sstart,
                                                       int* __restrict__ counts_new) {
    __shared__ int chn[N_PTS];
    __shared__ int chp[N_PTS];
    __shared__ int acnt[K_C], scnt[K_C], hcnt[K_C];
    __shared__ int ast[K_C + 1], sst[K_C + 1];
    const int t = threadIdx.x;
    if (t < K_C) { acnt[t] = 0; scnt[t] = 0; hcnt[t] = 0; }
    __syncthreads();
    const int cn = ch_new[t], cp = ch_prev[t];
    chn[t] = cn; chp[t] = cp;
    atomicAdd(&hcnt[cn], 1);
    const bool changed = (cn != cp);
    if (changed) {
        atomicAdd(&acnt[cn], 1);
        if (cp >= 0) atomicAdd(&scnt[cp], 1);
    }
    __syncthreads();
    if (t == 0) {
        int a = 0;
        for (int k = 0; k < K_C; ++k) { ast[k] = a; a += acnt[k]; }
        ast[K_C] = a;
    }
    if (t == 1 || blockDim.x == 1) { }
    if (t == 64) {
        int a = 0;
        for (int k = 0; k < K_C; ++k) { sst[k] = a; a += scnt[k]; }
        sst[K_C] = a;
    }
    __syncthreads();
    int ra = 0, rs = 0;
    for (int m = 0; m < t; ++m) {
        int cm = chn[m], pm = chp[m];
        bool ch = (cm != pm);
        ra += (ch && cm == cn);
        rs += (ch && pm == cp);
    }
    if (changed) {
        add_n[ast[cn] + ra] = t;
        if (cp >= 0) sub_n[sst[cp] + rs] = t;
    }
    if (t <= K_C) { astart[t] = ast[t]; sstart[t] = sst[t]; }
    if (t < K_C) counts_new[t] = hcnt[t];
}

// ---------------- incremental update via sorted add/sub lists ----------------
// sum = state*cp + sum(adds) - sum(subs), ascending-n per list (deterministic).
__global__ __launch_bounds__(256) void update_kernel(const float* __restrict__ X,
                                                     const int* __restrict__ add_n,
                                                     const int* __restrict__ astart,
                                                     const int* __restrict__ sub_n,
                                                     const int* __restrict__ sstart,
                                                     const int* __restrict__ counts_new,
                                                     const int* __restrict__ counts_prev,
                                                     float* __restrict__ state) {
    const int k = blockIdx.x;
    const int ab = astart[k], ae = astart[k + 1];
    const int sb = sstart[k], se = sstart[k + 1];
    if (ab == ae && sb == se) return;            // untouched: keep old state
    const int cn = counts_new[k], cp = counts_prev[k];
    const size_t d = (size_t)blockIdx.y * 1024 + threadIdx.x * 4;
    float* sp = state + (size_t)k * D_DIM + d;

    float sx = 0.f, sy = 0.f, sz = 0.f, sw = 0.f;
    if (cp > 0) {
        float4 st = *reinterpret_cast<const float4*>(sp);
        float c = (float)cp;
        sx = st.x * c; sy = st.y * c; sz = st.z * c; sw = st.w * c;
    }
    for (int i = ab; i < ae; ++i) {
        const float4 v = *reinterpret_cast<const float4*>(X + (size_t)add_n[i] * D_DIM + d);
        sx += v.x; sy += v.y; sz += v.z; sw += v.w;
    }
    for (int i = sb; i < se; ++i) {
        const float4 v = *reinterpret_cast<const float4*>(X + (size_t)sub_n[i] * D_DIM + d);
        sx -= v.x; sy -= v.y; sz -= v.z; sw -= v.w;
    }
    if (cn > 0) {
        float inv = 1.f / (float)cn;
        float4 o; o.x = sx * inv; o.y = sy * inv; o.z = sz * inv; o.w = sw * inv;
        *reinterpret_cast<float4*>(sp) = o;
    }
}

// ---------------- write last-iteration assignments as float ----------------
__global__ __launch_bounds__(256) void choice_out_kernel(const int* __restrict__ choice,
                                                         float* __restrict__ out) {
    int n = blockIdx.x * 256 + threadIdx.x;
    if (n < N_PTS) out[n] = (float)choice[n];
}

extern "C" void kernel_launch(void* const* d_in, const int* in_sizes, int n_in,
                              void* d_out, int out_size, void* d_ws, size_t ws_size,
                              hipStream_t stream) {
    const float* X  = (const float*)d_in[0];
    const float* C0 = (const float*)d_in[1];
    float* state      = (float*)d_out;
    float* out_choice = state + (size_t)K_C * D_DIM;

    // workspace (~446 MB of the ~1.5 GiB ws)
    char* w = (char*)d_ws;
    size_t off = 0;
    auto alloc = [&](size_t bytes) { void* p = w + off; off = (off + bytes + 255) & ~(size_t)255; return p; };
    unsigned short* Xh = (unsigned short*)alloc((size_t)N_PTS * D_DIM * 2);
    unsigned short* Xl = (unsigned short*)alloc((size_t)N_PTS * D_DIM * 2);
    unsigned short* Sh = (unsigned short*)alloc((size_t)K_C * D_DIM * 2);
    unsigned short* Sl = (unsigned short*)alloc((size_t)K_C * D_DIM * 2);
    float* partial = (float*)alloc((size_t)SPLITD * N_PTS * K_C * 4);   // 16 MB
    float* dotb    = (float*)alloc((size_t)N_PTS * K_C * 4);
    float* x2p     = (float*)alloc((size_t)N_PTS * CCHK * 4);
    float* x2      = (float*)alloc((size_t)N_PTS * 4);
    float* c2p     = (float*)alloc((size_t)K_C * CCHK * 4);
    int* cpts      = (int*)alloc(256);
    int* ch[2];
    ch[0] = (int*)alloc((size_t)N_PTS * 4);
    ch[1] = (int*)alloc((size_t)N_PTS * 4);
    int* ct[2];
    ct[0] = (int*)alloc(256);
    ct[1] = (int*)alloc(256);
    int* add_n  = (int*)alloc((size_t)N_PTS * 4);
    int* astart = (int*)alloc(512);
    int* sub_n  = (int*)alloc((size_t)N_PTS * 4);
    int* sstart = (int*)alloc(512);

    dim3 b256(256);

    // one-time: X -> bf16 hi/lo planes + x2
    convert_kernel<<<dim3(N_PTS, CCHK), b256, 0, stream>>>(X, Xh, Xl, x2p);
    reduce_sq_kernel<<<dim3(4), b256, 0, stream>>>(x2p, x2, N_PTS);

    // ---- init ('resuming'): snap each centroid to its nearest sample ----
    convert_kernel<<<dim3(K_C, CCHK), b256, 0, stream>>>(C0, Sh, Sl, c2p);
    mfma_dot_kernel<<<dim3(SPLITD, N_PTS / BM), b256, 0, stream>>>(Xh, Xl, Sh, Sl, partial);
    reduce_dot_kernel<<<dim3(N_PTS * K_C / 256), b256, 0, stream>>>(partial, dotb);
    argmin_n_kernel<<<K_C, b256, 0, stream>>>(dotb, x2, cpts);
    gather_kernel<<<dim3(K_C, NCHK), b256, 0, stream>>>(X, cpts, state);
    init_prev_kernel<<<dim3(4), b256, 0, stream>>>(ch[0], ct[0]);

    // ---- 10 Lloyd iterations ----
    for (int it = 0; it < ITERS; ++it) {
        int prev = it & 1, cur = 1 - prev;
        convert_kernel<<<dim3(K_C, CCHK), b256, 0, stream>>>(state, Sh, Sl, c2p);
        mfma_dot_kernel<<<dim3(SPLITD, N_PTS / BM), b256, 0, stream>>>(Xh, Xl, Sh, Sl, partial);
        assign_kernel<<<dim3(N_PTS / 4), b256, 0, stream>>>(partial, c2p, ch[cur]);
        changes_kernel<<<1, dim3(1024), 0, stream>>>(ch[cur], ch[prev], add_n, astart,
                                                     sub_n, sstart, ct[cur]);
        update_kernel<<<dim3(K_C, NCHK), b256, 0, stream>>>(X, add_n, astart, sub_n, sstart,
                                                            ct[cur], ct[prev], state);
    }

    choice_out_kernel<<<dim3(N_PTS / 256), b256, 0, stream>>>(ch[0], out_choice);
}